// Round 4
// baseline (277.754 us; speedup 1.0000x reference)
//
#include <hip/hip_runtime.h>

// ---------------------------------------------------------------------------
// SelfAttention with KV cache, MI355X (gfx950).
// B=4, T=2048, C=1024, T_PAST=2048, T_TOT=4096.
// Mask tril(ones(T, T_total)) -> row t attends j<=t only => only past_k/v.
// Launches (7):
//   1. cvt_all: x,Wq,Wk,Wv -> bf16 ; past_k -> bf16 kb       (one kernel)
//   2. v_copy_transpose: past_v -> outV rows [0,2048) AND VT bf16 [b][c][s]
//   3. proj_qv: Q=(xWq^T+bq)/32 -> bf16 qb ; V_new -> outV rows [2048,4096)
//   4. score_gemm: S = Q.kb^T -> BF16, stored in outK rows [0,2048) (scratch)
//   5. softmax: bf16 row -> bf16 P row in place (zeros beyond col t)
//   6. pv_gemm: out = P @ VT
//   7. proj_k_copy: K_new -> outK rows [2048,4096) + copy past_k -> rows [0,2048)
// S-bf16 (4 x 2048 x 2048 u16 = 33.5MB) == outK rows [0,2048) footprint exactly;
// step 7's copy overwrites it only after pv consumed it (stream order).
// All GEMMs: 128x128 tile, BK=32, 4 waves (2x2), global_load_lds w=16 into
// LINEAR LDS [128][32] (m97 structure).
// ---------------------------------------------------------------------------

typedef __bf16 bf16x8 __attribute__((ext_vector_type(8)));
typedef float f32x4 __attribute__((ext_vector_type(4)));

#define BB   4
#define TQ   2048
#define CD   1024
#define TPAST 2048
#define TTOT 4096
#define MROWS (BB * TQ)        // 8192

__device__ __forceinline__ unsigned short f32_to_bf16u(float f) {
  unsigned int u = __float_as_uint(f);
  u += 0x7FFFu + ((u >> 16) & 1u);       // RNE
  return (unsigned short)(u >> 16);
}
__device__ __forceinline__ float bf16u_to_f32(unsigned short h) {
  unsigned int u = ((unsigned int)h) << 16;
  return __uint_as_float(u);
}
__device__ __forceinline__ unsigned int pack_bf16(float a, float b) {
  return (unsigned int)f32_to_bf16u(a) | ((unsigned int)f32_to_bf16u(b) << 16);
}

// async global->LDS, 16B per lane; LDS dest = wave-uniform base + lane*16
__device__ __forceinline__ void gload_lds16(const unsigned short* g,
                                            unsigned short* l) {
  __builtin_amdgcn_global_load_lds(
      (const __attribute__((address_space(1))) void*)g,
      (__attribute__((address_space(3))) void*)l, 16, 0, 0);
}

// ---- one-shot f32->bf16 for x, Wq, Wk, Wv, past_k --------------------------
#define R0_END 2097152            // x     : 8192*1024/4 f4
#define R1_END 2359296            // Wq    : +262144
#define R2_END 2621440            // Wk
#define R3_END 2883584            // Wv
#define R4_END 4980736            // past_k: +2097152
__global__ __launch_bounds__(256) void cvt_all(
    const float* __restrict__ x, const float* __restrict__ wq,
    const float* __restrict__ wk, const float* __restrict__ wv,
    const float* __restrict__ pk,
    unsigned short* __restrict__ xb, unsigned short* __restrict__ wqb,
    unsigned short* __restrict__ wkb, unsigned short* __restrict__ wvb,
    unsigned short* __restrict__ kb) {
  int i = blockIdx.x * 256 + threadIdx.x;
  const float* src; unsigned short* dst; int off;
  if (i < R0_END)      { src = x;  dst = xb;  off = i; }
  else if (i < R1_END) { src = wq; dst = wqb; off = i - R0_END; }
  else if (i < R2_END) { src = wk; dst = wkb; off = i - R1_END; }
  else if (i < R3_END) { src = wv; dst = wvb; off = i - R2_END; }
  else                 { src = pk; dst = kb;  off = i - R3_END; }
  float4 f = ((const float4*)src)[off];
  uint2 o;
  o.x = pack_bf16(f.x, f.y);
  o.y = pack_bf16(f.z, f.w);
  ((uint2*)dst)[off] = o;
}

// ---- fused: past_v -> outV copy + bf16 transpose VT[b][c][s] ----------------
#define TP_PAD 134
__global__ __launch_bounds__(256) void v_copy_transpose(
    const float* __restrict__ pV, float* __restrict__ outV,
    unsigned short* __restrict__ VT) {
  __shared__ unsigned short T[32 * TP_PAD];
  const int s0 = blockIdx.x * 32, c0 = blockIdx.y * 128, b = blockIdx.z;
  const int tid = threadIdx.x;
  const int s = tid >> 3, i8 = tid & 7;
  const float* src = &pV[(size_t)(b * TPAST + s0 + s) * CD + c0];
  float* dst = &outV[(size_t)b * (TTOT * CD) + (size_t)(s0 + s) * CD + c0];
#pragma unroll
  for (int k = 0; k < 4; ++k) {
    int c = k * 32 + i8 * 4;
    float4 f = *(const float4*)&src[c];
    *(float4*)&dst[c] = f;
    *(unsigned int*)&T[s * TP_PAD + c]     = pack_bf16(f.x, f.y);
    *(unsigned int*)&T[s * TP_PAD + c + 2] = pack_bf16(f.z, f.w);
  }
  __syncthreads();
  const int c = tid >> 2, sq = tid & 3;
#pragma unroll
  for (int ii = 0; ii < 2; ++ii) {
    int cc = c + ii * 64;
    unsigned short tmp[8];
#pragma unroll
    for (int j = 0; j < 8; ++j) tmp[j] = T[(sq * 8 + j) * TP_PAD + cc];
    *(uint4*)&VT[(size_t)(b * CD + c0 + cc) * TPAST + s0 + sq * 8] = *(uint4*)tmp;
  }
}

// ---- merged Q+V projection: y<8 -> Q (bf16, scaled); y>=8 -> V_new (f32) ---
__global__ __launch_bounds__(256) void proj_qv(
    const unsigned short* __restrict__ A,    // x bf16 [8192][1024]
    const unsigned short* __restrict__ Wq_,  // bf16 [1024][1024]
    const unsigned short* __restrict__ Wv_,
    const float* __restrict__ bq_, const float* __restrict__ bv_,
    unsigned short* __restrict__ outQ,       // bf16 [8192][1024]
    float* __restrict__ outV) {              // f32 cache base (4,4096,1024)
  __shared__ unsigned short sA[128 * 32];
  __shared__ unsigned short sB[128 * 32];
  const int tm = blockIdx.x * 128;
  const bool isQ = blockIdx.y < 8;
  const int tn = (isQ ? blockIdx.y : blockIdx.y - 8) * 128;
  const unsigned short* W = isQ ? Wq_ : Wv_;
  const float* bias = isQ ? bq_ : bv_;
  const int tid = threadIdx.x, lane = tid & 63, wv = tid >> 6;
  const int wr = wv >> 1, wc = wv & 1;
  const int gr = lane >> 2, gc = (lane & 3) * 8;
  const unsigned short* aSrc = &A[(size_t)(tm + wv * 32 + gr) * CD + gc];
  const unsigned short* bSrc = &W[(size_t)(tn + wv * 32 + gr) * CD + gc];
  unsigned short* aDst = &sA[wv * 32 * 32];
  unsigned short* bDst = &sB[wv * 32 * 32];
  f32x4 acc[4][4] = {};
  for (int k0 = 0; k0 < CD; k0 += 32) {
    gload_lds16(aSrc + k0, aDst);
    gload_lds16(aSrc + k0 + (size_t)16 * CD, aDst + 16 * 32);
    gload_lds16(bSrc + k0, bDst);
    gload_lds16(bSrc + k0 + (size_t)16 * CD, bDst + 16 * 32);
    __syncthreads();
    bf16x8 af[4], bg[4];
    const int koff = (lane >> 4) * 8;
#pragma unroll
    for (int i = 0; i < 4; ++i)
      af[i] = *(const bf16x8*)&sA[(wr * 64 + i * 16 + (lane & 15)) * 32 + koff];
#pragma unroll
    for (int i = 0; i < 4; ++i)
      bg[i] = *(const bf16x8*)&sB[(wc * 64 + i * 16 + (lane & 15)) * 32 + koff];
#pragma unroll
    for (int mi = 0; mi < 4; ++mi)
#pragma unroll
      for (int ni = 0; ni < 4; ++ni)
        acc[mi][ni] = __builtin_amdgcn_mfma_f32_16x16x32_bf16(
            af[mi], bg[ni], acc[mi][ni], 0, 0, 0);
    __syncthreads();
  }
  const int rsub = (lane >> 4) * 4, csub = lane & 15;
#pragma unroll
  for (int mi = 0; mi < 4; ++mi)
#pragma unroll
    for (int ni = 0; ni < 4; ++ni) {
      int gcn = tn + wc * 64 + ni * 16 + csub;
      float bvv = bias[gcn];
#pragma unroll
      for (int r = 0; r < 4; ++r) {
        int grw = tm + wr * 64 + mi * 16 + rsub + r;
        float v = acc[mi][ni][r] + bvv;
        if (isQ) {
          outQ[(size_t)grw * CD + gcn] = f32_to_bf16u(v * 0.03125f);  // 1/sqrt(1024)
        } else {
          int b = grw >> 11, t = grw & (TQ - 1);
          outV[(size_t)b * (TTOT * CD) + (size_t)(TPAST + t) * CD + gcn] = v;
        }
      }
    }
}

// ---- scores: S16[b][t][s] = bf16( Q_scaled[b,t,:] . kb[b,s,:] ) ------------
__global__ __launch_bounds__(256) void score_gemm(
    const unsigned short* __restrict__ Q,   // bf16 [8192][1024], pre-scaled
    const unsigned short* __restrict__ KB,  // bf16 [4][2048][1024]
    unsigned short* __restrict__ S16) {     // bf16 [4][2048][2048]
  const int t0 = blockIdx.x * 128, s0 = blockIdx.y * 128, b = blockIdx.z;
  if (s0 > t0 + 127) return;
  __shared__ unsigned short sA[128 * 32];
  __shared__ unsigned short sB[128 * 32];
  const int tid = threadIdx.x, lane = tid & 63, wv = tid >> 6;
  const int wr = wv >> 1, wc = wv & 1;
  const int gr = lane >> 2, gc = (lane & 3) * 8;
  const unsigned short* aSrc = &Q[(size_t)(b * TQ + t0 + wv * 32 + gr) * CD + gc];
  const unsigned short* bSrc = &KB[(size_t)(b * TPAST + s0 + wv * 32 + gr) * CD + gc];
  unsigned short* aDst = &sA[wv * 32 * 32];
  unsigned short* bDst = &sB[wv * 32 * 32];
  f32x4 acc[4][4] = {};
  for (int k0 = 0; k0 < CD; k0 += 32) {
    gload_lds16(aSrc + k0, aDst);
    gload_lds16(aSrc + k0 + (size_t)16 * CD, aDst + 16 * 32);
    gload_lds16(bSrc + k0, bDst);
    gload_lds16(bSrc + k0 + (size_t)16 * CD, bDst + 16 * 32);
    __syncthreads();
    bf16x8 af[4], bg[4];
    const int koff = (lane >> 4) * 8;
#pragma unroll
    for (int i = 0; i < 4; ++i)
      af[i] = *(const bf16x8*)&sA[(wr * 64 + i * 16 + (lane & 15)) * 32 + koff];
#pragma unroll
    for (int i = 0; i < 4; ++i)
      bg[i] = *(const bf16x8*)&sB[(wc * 64 + i * 16 + (lane & 15)) * 32 + koff];
#pragma unroll
    for (int mi = 0; mi < 4; ++mi)
#pragma unroll
      for (int ni = 0; ni < 4; ++ni)
        acc[mi][ni] = __builtin_amdgcn_mfma_f32_16x16x32_bf16(
            af[mi], bg[ni], acc[mi][ni], 0, 0, 0);
    __syncthreads();
  }
  const int rsub = (lane >> 4) * 4, csub = lane & 15;
#pragma unroll
  for (int mi = 0; mi < 4; ++mi)
#pragma unroll
    for (int ni = 0; ni < 4; ++ni) {
      int gs = s0 + wc * 64 + ni * 16 + csub;
#pragma unroll
      for (int r = 0; r < 4; ++r) {
        int gt = t0 + wr * 64 + mi * 16 + rsub + r;
        S16[(size_t)b * (TQ * TPAST) + (size_t)gt * TPAST + gs] =
            f32_to_bf16u(acc[mi][ni][r]);
      }
    }
}

// ---- row softmax on bf16 S, in place -> bf16 P (zeros beyond col t) --------
__global__ __launch_bounds__(256) void softmax_kernel(unsigned short* __restrict__ S16) {
  const int row = blockIdx.x;               // 0..8191
  const int b = row >> 11, t = row & (TQ - 1);
  unsigned short* p = S16 + (size_t)b * (TQ * TPAST) + (size_t)t * TPAST;
  const int tid = threadIdx.x, lane = tid & 63, wv = tid >> 6;
  __shared__ float red[8];
  const int base = tid * 8;
  uint4 raw = *(const uint4*)&p[base];
  const unsigned short* rw = (const unsigned short*)&raw;
  float v[8];
  float m = -3.0e38f;
#pragma unroll
  for (int i = 0; i < 8; ++i) {
    v[i] = (base + i <= t) ? bf16u_to_f32(rw[i]) : -3.0e38f;
    m = fmaxf(m, v[i]);
  }
#pragma unroll
  for (int off = 32; off >= 1; off >>= 1) m = fmaxf(m, __shfl_down(m, off));
  if (lane == 0) red[wv] = m;
  __syncthreads();
  if (tid == 0) red[4] = fmaxf(fmaxf(red[0], red[1]), fmaxf(red[2], red[3]));
  __syncthreads();
  const float rm = red[4];
  float e[8], s = 0.f;
#pragma unroll
  for (int i = 0; i < 8; ++i) {
    e[i] = (base + i <= t) ? __expf(v[i] - rm) : 0.f;
    s += e[i];
  }
#pragma unroll
  for (int off = 32; off >= 1; off >>= 1) s += __shfl_down(s, off);
  __syncthreads();
  if (lane == 0) red[wv] = s;
  __syncthreads();
  if (tid == 0) red[5] = red[0] + red[1] + red[2] + red[3];
  __syncthreads();
  const float inv = 1.f / red[5];
  unsigned short ob[8];
#pragma unroll
  for (int i = 0; i < 8; ++i) ob[i] = f32_to_bf16u(e[i] * inv);
  *(uint4*)&p[base] = *(uint4*)ob;
}

// ---- out = P(bf16) @ VT(bf16) ; per batch M=2048, N=1024(c), K=s -----------
__global__ __launch_bounds__(256) void pv_gemm(
    const unsigned short* __restrict__ Pb,  // bf16 [4][2048][2048]
    const unsigned short* __restrict__ VT,  // bf16 [4][1024][2048]
    float* __restrict__ O) {                // f32 [4][2048][1024]
  const int t0 = blockIdx.x * 128, c0 = blockIdx.y * 128, b = blockIdx.z;
  __shared__ unsigned short sA[128 * 32];
  __shared__ unsigned short sB[128 * 32];
  const int tid = threadIdx.x, lane = tid & 63, wv = tid >> 6;
  const int wr = wv >> 1, wc = wv & 1;
  const int gr = lane >> 2, gc = (lane & 3) * 8;
  const unsigned short* aSrc =
      &Pb[(size_t)(b * TQ + t0 + wv * 32 + gr) * TPAST + gc];
  const unsigned short* bSrc =
      &VT[(size_t)(b * CD + c0 + wv * 32 + gr) * TPAST + gc];
  unsigned short* aDst = &sA[wv * 32 * 32];
  unsigned short* bDst = &sB[wv * 32 * 32];
  f32x4 acc[4][4] = {};
  const int s_end = (t0 + 128 < TPAST) ? (t0 + 128) : TPAST;  // P==0 past t
  for (int s0 = 0; s0 < s_end; s0 += 32) {
    gload_lds16(aSrc + s0, aDst);
    gload_lds16(aSrc + s0 + (size_t)16 * TPAST, aDst + 16 * 32);
    gload_lds16(bSrc + s0, bDst);
    gload_lds16(bSrc + s0 + (size_t)16 * TPAST, bDst + 16 * 32);
    __syncthreads();
    bf16x8 af[4], bg[4];
    const int koff = (lane >> 4) * 8;
#pragma unroll
    for (int i = 0; i < 4; ++i)
      af[i] = *(const bf16x8*)&sA[(wr * 64 + i * 16 + (lane & 15)) * 32 + koff];
#pragma unroll
    for (int i = 0; i < 4; ++i)
      bg[i] = *(const bf16x8*)&sB[(wc * 64 + i * 16 + (lane & 15)) * 32 + koff];
#pragma unroll
    for (int mi = 0; mi < 4; ++mi)
#pragma unroll
      for (int ni = 0; ni < 4; ++ni)
        acc[mi][ni] = __builtin_amdgcn_mfma_f32_16x16x32_bf16(
            af[mi], bg[ni], acc[mi][ni], 0, 0, 0);
    __syncthreads();
  }
  const int rsub = (lane >> 4) * 4, csub = lane & 15;
#pragma unroll
  for (int mi = 0; mi < 4; ++mi)
#pragma unroll
    for (int ni = 0; ni < 4; ++ni) {
      int gcn = c0 + wc * 64 + ni * 16 + csub;
#pragma unroll
      for (int r = 0; r < 4; ++r) {
        int gt = t0 + wr * 64 + mi * 16 + rsub + r;
        O[(size_t)(b * TQ + gt) * CD + gcn] = acc[mi][ni][r];
      }
    }
}

// ---- K_new projection (y<8) + past_k copy (y==8) ---------------------------
__global__ __launch_bounds__(256) void proj_k_copy(
    const unsigned short* __restrict__ A,   // x bf16 [8192][1024]
    const unsigned short* __restrict__ Wk_, // bf16 [1024][1024]
    const float* __restrict__ bk_,
    const float* __restrict__ pk,           // f32 [4][2048][1024]
    float* __restrict__ outK) {             // f32 cache base (4,4096,1024)
  const int tm = blockIdx.x * 128;
  if (blockIdx.y == 8) {                    // copy past_k rows tm..tm+127
    for (int j = threadIdx.x; j < 32768; j += 256) {
      int r = j >> 8, c4 = j & 255;
      int grow = tm + r;
      int b = grow >> 11, t = grow & (TQ - 1);
      ((float4*)outK)[((size_t)b * (TTOT * CD) + (size_t)t * CD) / 4 + c4] =
          ((const float4*)pk)[(size_t)grow * 256 + c4];
    }
    return;
  }
  __shared__ unsigned short sA[128 * 32];
  __shared__ unsigned short sB[128 * 32];
  const int tn = blockIdx.y * 128;
  const int tid = threadIdx.x, lane = tid & 63, wv = tid >> 6;
  const int wr = wv >> 1, wc = wv & 1;
  const int gr = lane >> 2, gc = (lane & 3) * 8;
  const unsigned short* aSrc = &A[(size_t)(tm + wv * 32 + gr) * CD + gc];
  const unsigned short* bSrc = &Wk_[(size_t)(tn + wv * 32 + gr) * CD + gc];
  unsigned short* aDst = &sA[wv * 32 * 32];
  unsigned short* bDst = &sB[wv * 32 * 32];
  f32x4 acc[4][4] = {};
  for (int k0 = 0; k0 < CD; k0 += 32) {
    gload_lds16(aSrc + k0, aDst);
    gload_lds16(aSrc + k0 + (size_t)16 * CD, aDst + 16 * 32);
    gload_lds16(bSrc + k0, bDst);
    gload_lds16(bSrc + k0 + (size_t)16 * CD, bDst + 16 * 32);
    __syncthreads();
    bf16x8 af[4], bg[4];
    const int koff = (lane >> 4) * 8;
#pragma unroll
    for (int i = 0; i < 4; ++i)
      af[i] = *(const bf16x8*)&sA[(wr * 64 + i * 16 + (lane & 15)) * 32 + koff];
#pragma unroll
    for (int i = 0; i < 4; ++i)
      bg[i] = *(const bf16x8*)&sB[(wc * 64 + i * 16 + (lane & 15)) * 32 + koff];
#pragma unroll
    for (int mi = 0; mi < 4; ++mi)
#pragma unroll
      for (int ni = 0; ni < 4; ++ni)
        acc[mi][ni] = __builtin_amdgcn_mfma_f32_16x16x32_bf16(
            af[mi], bg[ni], acc[mi][ni], 0, 0, 0);
    __syncthreads();
  }
  const int rsub = (lane >> 4) * 4, csub = lane & 15;
#pragma unroll
  for (int mi = 0; mi < 4; ++mi)
#pragma unroll
    for (int ni = 0; ni < 4; ++ni) {
      int gcn = tn + wc * 64 + ni * 16 + csub;
      float bvv = bk_[gcn];
#pragma unroll
      for (int r = 0; r < 4; ++r) {
        int grw = tm + wr * 64 + mi * 16 + rsub + r;
        int b = grw >> 11, t = grw & (TQ - 1);
        outK[(size_t)b * (TTOT * CD) + (size_t)(TPAST + t) * CD + gcn] =
            acc[mi][ni][r] + bvv;
      }
    }
}

extern "C" void kernel_launch(void* const* d_in, const int* in_sizes, int n_in,
                              void* d_out, int out_size, void* d_ws, size_t ws_size,
                              hipStream_t stream) {
  const float* x  = (const float*)d_in[0];
  const float* pk = (const float*)d_in[1];
  const float* pv = (const float*)d_in[2];
  const float* Wq = (const float*)d_in[3];
  const float* bq = (const float*)d_in[4];
  const float* Wk = (const float*)d_in[5];
  const float* bk = (const float*)d_in[6];
  const float* Wv = (const float*)d_in[7];
  const float* bv = (const float*)d_in[8];

  float* out  = (float*)d_out;                       // (4,2048,1024)
  float* outK = out + (size_t)BB * TQ * CD;          // (4,4096,1024)
  float* outV = outK + (size_t)BB * TTOT * CD;       // (4,4096,1024)
  // S bf16 [4][2048][2048] overlays outK rows [0,2048) per batch (exact fit)
  unsigned short* S16 = (unsigned short*)outK;

  unsigned short* xb  = (unsigned short*)d_ws;       // 8192*1024 bf16
  unsigned short* wqb = xb + (size_t)MROWS * CD;
  unsigned short* wkb = wqb + (size_t)CD * CD;
  unsigned short* wvb = wkb + (size_t)CD * CD;
  unsigned short* qb  = wvb + (size_t)CD * CD;       // 8192*1024 bf16
  unsigned short* vtb = qb + (size_t)MROWS * CD;     // 4*1024*2048 bf16 (V^T)
  unsigned short* kb  = vtb + (size_t)BB * CD * TPAST; // 4*2048*1024 bf16

  // 1. all f32->bf16 conversions in one launch
  cvt_all<<<R4_END / 256, 256, 0, stream>>>(x, Wq, Wk, Wv, pk,
                                            xb, wqb, wkb, wvb, kb);
  // 2. past_v -> outV rows [0,2048) + VT bf16 transpose
  v_copy_transpose<<<dim3(TPAST / 32, CD / 128, BB), 256, 0, stream>>>(pv, outV, vtb);
  // 3. Q (bf16, scaled) + V_new (f32 rows 2048+)
  proj_qv<<<dim3(MROWS / 128, 16), 256, 0, stream>>>(xb, wqb, wvb, bq, bv, qb, outV);
  // 4. scores -> bf16 S in outK rows [0,2048)
  score_gemm<<<dim3(TQ / 128, TPAST / 128, BB), 256, 0, stream>>>(qb, kb, S16);
  // 5. softmax rows in place (bf16 -> bf16)
  softmax_kernel<<<BB * TQ, 256, 0, stream>>>(S16);
  // 6. out = P @ V via VT
  pv_gemm<<<dim3(TQ / 128, CD / 128, BB), 256, 0, stream>>>(S16, vtb, out);
  // 7. K_new -> outK rows [2048,4096) + past_k copy -> rows [0,2048)
  proj_k_copy<<<dim3(MROWS / 128, 9), 256, 0, stream>>>(xb, wkb, bk, pk, outK);
}

// Round 5
// 240.420 us; speedup vs baseline: 1.1553x; 1.1553x over previous
//
#include <hip/hip_runtime.h>

// ---------------------------------------------------------------------------
// SelfAttention with KV cache, MI355X (gfx950).
// B=4, T=2048, C=1024, T_PAST=2048, T_TOT=4096.
// Mask tril(ones(T, T_total)) -> row t attends j<=t only => only past_k/v.
// Launches (7):
//   1. cvt_all: x,Wq,Wk,Wv -> bf16 ; past_k -> bf16 kb
//   2. v_copy_transpose: past_v -> outV rows [0,2048) AND VT bf16 [b][c][s]
//   3. proj_qkv: Q->qb (bf16,scaled); V_new->outV rows[2048+); K_new->outK rows[2048+)
//   4. score_gemm: S = Q.kb^T -> bf16 S16 (overlay of outK rows [0,2048) PER BATCH)
//   5. softmax: bf16 row -> bf16 P row in place (zeros beyond col t)
//   6. pv_gemm: out = P @ VT
//   7. copy_past: pk -> outK rows [0,2048)  (wide grid; after pv consumed S16)
// S16 per-batch base = b * (TTOT*CD f32) so it overlays ONLY batch b's rows
// [0,2048) of outK -> K_new (rows 2048+) can be written early by proj_qkv.
// All GEMMs: 128x128 tile, BK=32, 4 waves (2x2), global_load_lds w=16 into
// LINEAR LDS [128][32] (m97 structure).
// ---------------------------------------------------------------------------

typedef __bf16 bf16x8 __attribute__((ext_vector_type(8)));
typedef float f32x4 __attribute__((ext_vector_type(4)));

#define BB   4
#define TQ   2048
#define CD   1024
#define TPAST 2048
#define TTOT 4096
#define MROWS (BB * TQ)        // 8192
#define SSTRIDE ((size_t)TTOT * CD * 2)   // u16 units per batch window (16MB)

__device__ __forceinline__ unsigned short f32_to_bf16u(float f) {
  unsigned int u = __float_as_uint(f);
  u += 0x7FFFu + ((u >> 16) & 1u);       // RNE
  return (unsigned short)(u >> 16);
}
__device__ __forceinline__ float bf16u_to_f32(unsigned short h) {
  unsigned int u = ((unsigned int)h) << 16;
  return __uint_as_float(u);
}
__device__ __forceinline__ unsigned int pack_bf16(float a, float b) {
  return (unsigned int)f32_to_bf16u(a) | ((unsigned int)f32_to_bf16u(b) << 16);
}

// async global->LDS, 16B per lane; LDS dest = wave-uniform base + lane*16
__device__ __forceinline__ void gload_lds16(const unsigned short* g,
                                            unsigned short* l) {
  __builtin_amdgcn_global_load_lds(
      (const __attribute__((address_space(1))) void*)g,
      (__attribute__((address_space(3))) void*)l, 16, 0, 0);
}

// ---- one-shot f32->bf16 for x, Wq, Wk, Wv, past_k --------------------------
#define R0_END 2097152            // x     : 8192*1024/4 f4
#define R1_END 2359296            // Wq    : +262144
#define R2_END 2621440            // Wk
#define R3_END 2883584            // Wv
#define R4_END 4980736            // past_k: +2097152
__global__ __launch_bounds__(256) void cvt_all(
    const float* __restrict__ x, const float* __restrict__ wq,
    const float* __restrict__ wk, const float* __restrict__ wv,
    const float* __restrict__ pk,
    unsigned short* __restrict__ xb, unsigned short* __restrict__ wqb,
    unsigned short* __restrict__ wkb, unsigned short* __restrict__ wvb,
    unsigned short* __restrict__ kb) {
  int i = blockIdx.x * 256 + threadIdx.x;
  const float* src; unsigned short* dst; int off;
  if (i < R0_END)      { src = x;  dst = xb;  off = i; }
  else if (i < R1_END) { src = wq; dst = wqb; off = i - R0_END; }
  else if (i < R2_END) { src = wk; dst = wkb; off = i - R1_END; }
  else if (i < R3_END) { src = wv; dst = wvb; off = i - R2_END; }
  else                 { src = pk; dst = kb;  off = i - R3_END; }
  float4 f = ((const float4*)src)[off];
  uint2 o;
  o.x = pack_bf16(f.x, f.y);
  o.y = pack_bf16(f.z, f.w);
  ((uint2*)dst)[off] = o;
}

// ---- copy past (4,2048,1024) into cache region (4,4096,1024) rows [0,2048) -
__global__ __launch_bounds__(256) void copy_past_kernel(
    const float* __restrict__ src, float* __restrict__ dst) {
  int i = blockIdx.x * 256 + threadIdx.x;      // float4 units
  int b = i >> 19;                             // 524288 units per batch
  int rem = i & 524287;
  ((float4*)dst)[(size_t)b * 1048576 + rem] = ((const float4*)src)[i];
}

// ---- fused: past_v -> outV copy + bf16 transpose VT[b][c][s] ----------------
#define TP_PAD 134
__global__ __launch_bounds__(256) void v_copy_transpose(
    const float* __restrict__ pV, float* __restrict__ outV,
    unsigned short* __restrict__ VT) {
  __shared__ unsigned short T[32 * TP_PAD];
  const int s0 = blockIdx.x * 32, c0 = blockIdx.y * 128, b = blockIdx.z;
  const int tid = threadIdx.x;
  const int s = tid >> 3, i8 = tid & 7;
  const float* src = &pV[(size_t)(b * TPAST + s0 + s) * CD + c0];
  float* dst = &outV[(size_t)b * (TTOT * CD) + (size_t)(s0 + s) * CD + c0];
#pragma unroll
  for (int k = 0; k < 4; ++k) {
    int c = k * 32 + i8 * 4;
    float4 f = *(const float4*)&src[c];
    *(float4*)&dst[c] = f;
    *(unsigned int*)&T[s * TP_PAD + c]     = pack_bf16(f.x, f.y);
    *(unsigned int*)&T[s * TP_PAD + c + 2] = pack_bf16(f.z, f.w);
  }
  __syncthreads();
  const int c = tid >> 2, sq = tid & 3;
#pragma unroll
  for (int ii = 0; ii < 2; ++ii) {
    int cc = c + ii * 64;
    unsigned short tmp[8];
#pragma unroll
    for (int j = 0; j < 8; ++j) tmp[j] = T[(sq * 8 + j) * TP_PAD + cc];
    *(uint4*)&VT[(size_t)(b * CD + c0 + cc) * TPAST + s0 + sq * 8] = *(uint4*)tmp;
  }
}

// ---- merged Q+V+K projection -----------------------------------------------
// y in [0,8): Q (bf16, scaled 1/32) -> qb
// y in [8,16): V_new (f32) -> outV rows [2048,4096)
// y in [16,24): K_new (f32) -> outK rows [2048,4096)  (disjoint from S16 overlay)
__global__ __launch_bounds__(256) void proj_qkv(
    const unsigned short* __restrict__ A,    // x bf16 [8192][1024]
    const unsigned short* __restrict__ Wq_,
    const unsigned short* __restrict__ Wv_,
    const unsigned short* __restrict__ Wk_,
    const float* __restrict__ bq_, const float* __restrict__ bv_,
    const float* __restrict__ bk_,
    unsigned short* __restrict__ outQ,       // bf16 [8192][1024]
    float* __restrict__ outV,                // f32 cache base (4,4096,1024)
    float* __restrict__ outK) {              // f32 cache base (4,4096,1024)
  __shared__ unsigned short sA[128 * 32];
  __shared__ unsigned short sB[128 * 32];
  const int tm = blockIdx.x * 128;
  const int which = blockIdx.y >> 3;         // 0=Q, 1=V, 2=K
  const int tn = (blockIdx.y & 7) * 128;
  const unsigned short* W = (which == 0) ? Wq_ : (which == 1) ? Wv_ : Wk_;
  const float* bias = (which == 0) ? bq_ : (which == 1) ? bv_ : bk_;
  const int tid = threadIdx.x, lane = tid & 63, wv = tid >> 6;
  const int wr = wv >> 1, wc = wv & 1;
  const int gr = lane >> 2, gc = (lane & 3) * 8;
  const unsigned short* aSrc = &A[(size_t)(tm + wv * 32 + gr) * CD + gc];
  const unsigned short* bSrc = &W[(size_t)(tn + wv * 32 + gr) * CD + gc];
  unsigned short* aDst = &sA[wv * 32 * 32];
  unsigned short* bDst = &sB[wv * 32 * 32];
  f32x4 acc[4][4] = {};
  for (int k0 = 0; k0 < CD; k0 += 32) {
    gload_lds16(aSrc + k0, aDst);
    gload_lds16(aSrc + k0 + (size_t)16 * CD, aDst + 16 * 32);
    gload_lds16(bSrc + k0, bDst);
    gload_lds16(bSrc + k0 + (size_t)16 * CD, bDst + 16 * 32);
    __syncthreads();
    bf16x8 af[4], bg[4];
    const int koff = (lane >> 4) * 8;
#pragma unroll
    for (int i = 0; i < 4; ++i)
      af[i] = *(const bf16x8*)&sA[(wr * 64 + i * 16 + (lane & 15)) * 32 + koff];
#pragma unroll
    for (int i = 0; i < 4; ++i)
      bg[i] = *(const bf16x8*)&sB[(wc * 64 + i * 16 + (lane & 15)) * 32 + koff];
#pragma unroll
    for (int mi = 0; mi < 4; ++mi)
#pragma unroll
      for (int ni = 0; ni < 4; ++ni)
        acc[mi][ni] = __builtin_amdgcn_mfma_f32_16x16x32_bf16(
            af[mi], bg[ni], acc[mi][ni], 0, 0, 0);
    __syncthreads();
  }
  const int rsub = (lane >> 4) * 4, csub = lane & 15;
#pragma unroll
  for (int mi = 0; mi < 4; ++mi)
#pragma unroll
    for (int ni = 0; ni < 4; ++ni) {
      int gcn = tn + wc * 64 + ni * 16 + csub;
      float bvv = bias[gcn];
#pragma unroll
      for (int r = 0; r < 4; ++r) {
        int grw = tm + wr * 64 + mi * 16 + rsub + r;
        float v = acc[mi][ni][r] + bvv;
        if (which == 0) {
          outQ[(size_t)grw * CD + gcn] = f32_to_bf16u(v * 0.03125f);  // 1/sqrt(1024)
        } else {
          int b = grw >> 11, t = grw & (TQ - 1);
          float* o = (which == 1) ? outV : outK;
          o[(size_t)b * (TTOT * CD) + (size_t)(TPAST + t) * CD + gcn] = v;
        }
      }
    }
}

// ---- scores: S16[b][t][s] = bf16( Q_scaled[b,t,:] . kb[b,s,:] ) ------------
__global__ __launch_bounds__(256) void score_gemm(
    const unsigned short* __restrict__ Q,   // bf16 [8192][1024], pre-scaled
    const unsigned short* __restrict__ KB,  // bf16 [4][2048][1024]
    unsigned short* __restrict__ S16) {     // bf16, per-batch window SSTRIDE
  const int t0 = blockIdx.x * 128, s0 = blockIdx.y * 128, b = blockIdx.z;
  if (s0 > t0 + 127) return;
  __shared__ unsigned short sA[128 * 32];
  __shared__ unsigned short sB[128 * 32];
  const int tid = threadIdx.x, lane = tid & 63, wv = tid >> 6;
  const int wr = wv >> 1, wc = wv & 1;
  const int gr = lane >> 2, gc = (lane & 3) * 8;
  const unsigned short* aSrc = &Q[(size_t)(b * TQ + t0 + wv * 32 + gr) * CD + gc];
  const unsigned short* bSrc = &KB[(size_t)(b * TPAST + s0 + wv * 32 + gr) * CD + gc];
  unsigned short* aDst = &sA[wv * 32 * 32];
  unsigned short* bDst = &sB[wv * 32 * 32];
  f32x4 acc[4][4] = {};
  for (int k0 = 0; k0 < CD; k0 += 32) {
    gload_lds16(aSrc + k0, aDst);
    gload_lds16(aSrc + k0 + (size_t)16 * CD, aDst + 16 * 32);
    gload_lds16(bSrc + k0, bDst);
    gload_lds16(bSrc + k0 + (size_t)16 * CD, bDst + 16 * 32);
    __syncthreads();
    bf16x8 af[4], bg[4];
    const int koff = (lane >> 4) * 8;
#pragma unroll
    for (int i = 0; i < 4; ++i)
      af[i] = *(const bf16x8*)&sA[(wr * 64 + i * 16 + (lane & 15)) * 32 + koff];
#pragma unroll
    for (int i = 0; i < 4; ++i)
      bg[i] = *(const bf16x8*)&sB[(wc * 64 + i * 16 + (lane & 15)) * 32 + koff];
#pragma unroll
    for (int mi = 0; mi < 4; ++mi)
#pragma unroll
      for (int ni = 0; ni < 4; ++ni)
        acc[mi][ni] = __builtin_amdgcn_mfma_f32_16x16x32_bf16(
            af[mi], bg[ni], acc[mi][ni], 0, 0, 0);
    __syncthreads();
  }
  const int rsub = (lane >> 4) * 4, csub = lane & 15;
#pragma unroll
  for (int mi = 0; mi < 4; ++mi)
#pragma unroll
    for (int ni = 0; ni < 4; ++ni) {
      int gs = s0 + wc * 64 + ni * 16 + csub;
#pragma unroll
      for (int r = 0; r < 4; ++r) {
        int gt = t0 + wr * 64 + mi * 16 + rsub + r;
        S16[(size_t)b * SSTRIDE + (size_t)gt * TPAST + gs] =
            f32_to_bf16u(acc[mi][ni][r]);
      }
    }
}

// ---- row softmax on bf16 S, in place -> bf16 P (zeros beyond col t) --------
__global__ __launch_bounds__(256) void softmax_kernel(unsigned short* __restrict__ S16) {
  const int row = blockIdx.x;               // 0..8191
  const int b = row >> 11, t = row & (TQ - 1);
  unsigned short* p = S16 + (size_t)b * SSTRIDE + (size_t)t * TPAST;
  const int tid = threadIdx.x, lane = tid & 63, wv = tid >> 6;
  __shared__ float red[8];
  const int base = tid * 8;
  uint4 raw = *(const uint4*)&p[base];
  const unsigned short* rw = (const unsigned short*)&raw;
  float v[8];
  float m = -3.0e38f;
#pragma unroll
  for (int i = 0; i < 8; ++i) {
    v[i] = (base + i <= t) ? bf16u_to_f32(rw[i]) : -3.0e38f;
    m = fmaxf(m, v[i]);
  }
#pragma unroll
  for (int off = 32; off >= 1; off >>= 1) m = fmaxf(m, __shfl_down(m, off));
  if (lane == 0) red[wv] = m;
  __syncthreads();
  if (tid == 0) red[4] = fmaxf(fmaxf(red[0], red[1]), fmaxf(red[2], red[3]));
  __syncthreads();
  const float rm = red[4];
  float e[8], s = 0.f;
#pragma unroll
  for (int i = 0; i < 8; ++i) {
    e[i] = (base + i <= t) ? __expf(v[i] - rm) : 0.f;
    s += e[i];
  }
#pragma unroll
  for (int off = 32; off >= 1; off >>= 1) s += __shfl_down(s, off);
  __syncthreads();
  if (lane == 0) red[wv] = s;
  __syncthreads();
  if (tid == 0) red[5] = red[0] + red[1] + red[2] + red[3];
  __syncthreads();
  const float inv = 1.f / red[5];
  unsigned short ob[8];
#pragma unroll
  for (int i = 0; i < 8; ++i) ob[i] = f32_to_bf16u(e[i] * inv);
  *(uint4*)&p[base] = *(uint4*)ob;
}

// ---- out = P(bf16) @ VT(bf16) ; per batch M=2048, N=1024(c), K=s -----------
__global__ __launch_bounds__(256) void pv_gemm(
    const unsigned short* __restrict__ Pb,  // bf16, per-batch window SSTRIDE
    const unsigned short* __restrict__ VT,  // bf16 [4][1024][2048]
    float* __restrict__ O) {                // f32 [4][2048][1024]
  const int t0 = blockIdx.x * 128, c0 = blockIdx.y * 128, b = blockIdx.z;
  __shared__ unsigned short sA[128 * 32];
  __shared__ unsigned short sB[128 * 32];
  const int tid = threadIdx.x, lane = tid & 63, wv = tid >> 6;
  const int wr = wv >> 1, wc = wv & 1;
  const int gr = lane >> 2, gc = (lane & 3) * 8;
  const unsigned short* aSrc =
      &Pb[(size_t)b * SSTRIDE + (size_t)(t0 + wv * 32 + gr) * TPAST + gc];
  const unsigned short* bSrc =
      &VT[(size_t)(b * CD + c0 + wv * 32 + gr) * TPAST + gc];
  unsigned short* aDst = &sA[wv * 32 * 32];
  unsigned short* bDst = &sB[wv * 32 * 32];
  f32x4 acc[4][4] = {};
  const int s_end = (t0 + 128 < TPAST) ? (t0 + 128) : TPAST;  // P==0 past t
  for (int s0 = 0; s0 < s_end; s0 += 32) {
    gload_lds16(aSrc + s0, aDst);
    gload_lds16(aSrc + s0 + (size_t)16 * TPAST, aDst + 16 * 32);
    gload_lds16(bSrc + s0, bDst);
    gload_lds16(bSrc + s0 + (size_t)16 * TPAST, bDst + 16 * 32);
    __syncthreads();
    bf16x8 af[4], bg[4];
    const int koff = (lane >> 4) * 8;
#pragma unroll
    for (int i = 0; i < 4; ++i)
      af[i] = *(const bf16x8*)&sA[(wr * 64 + i * 16 + (lane & 15)) * 32 + koff];
#pragma unroll
    for (int i = 0; i < 4; ++i)
      bg[i] = *(const bf16x8*)&sB[(wc * 64 + i * 16 + (lane & 15)) * 32 + koff];
#pragma unroll
    for (int mi = 0; mi < 4; ++mi)
#pragma unroll
      for (int ni = 0; ni < 4; ++ni)
        acc[mi][ni] = __builtin_amdgcn_mfma_f32_16x16x32_bf16(
            af[mi], bg[ni], acc[mi][ni], 0, 0, 0);
    __syncthreads();
  }
  const int rsub = (lane >> 4) * 4, csub = lane & 15;
#pragma unroll
  for (int mi = 0; mi < 4; ++mi)
#pragma unroll
    for (int ni = 0; ni < 4; ++ni) {
      int gcn = c0 + wc * 64 + ni * 16 + csub;
#pragma unroll
      for (int r = 0; r < 4; ++r) {
        int gt = t0 + wr * 64 + mi * 16 + rsub + r;
        O[(size_t)(b * TQ + gt) * CD + gcn] = acc[mi][ni][r];
      }
    }
}

extern "C" void kernel_launch(void* const* d_in, const int* in_sizes, int n_in,
                              void* d_out, int out_size, void* d_ws, size_t ws_size,
                              hipStream_t stream) {
  const float* x  = (const float*)d_in[0];
  const float* pk = (const float*)d_in[1];
  const float* pv = (const float*)d_in[2];
  const float* Wq = (const float*)d_in[3];
  const float* bq = (const float*)d_in[4];
  const float* Wk = (const float*)d_in[5];
  const float* bk = (const float*)d_in[6];
  const float* Wv = (const float*)d_in[7];
  const float* bv = (const float*)d_in[8];

  float* out  = (float*)d_out;                       // (4,2048,1024)
  float* outK = out + (size_t)BB * TQ * CD;          // (4,4096,1024)
  float* outV = outK + (size_t)BB * TTOT * CD;       // (4,4096,1024)
  // S16 bf16 [2048][2048] per batch, overlaying batch b's outK rows [0,2048)
  unsigned short* S16 = (unsigned short*)outK;

  unsigned short* xb  = (unsigned short*)d_ws;       // 8192*1024 bf16
  unsigned short* wqb = xb + (size_t)MROWS * CD;
  unsigned short* wkb = wqb + (size_t)CD * CD;
  unsigned short* wvb = wkb + (size_t)CD * CD;
  unsigned short* qb  = wvb + (size_t)CD * CD;       // 8192*1024 bf16
  unsigned short* vtb = qb + (size_t)MROWS * CD;     // 4*1024*2048 bf16 (V^T)
  unsigned short* kb  = vtb + (size_t)BB * CD * TPAST; // 4*2048*1024 bf16

  // 1. all f32->bf16 conversions in one launch
  cvt_all<<<R4_END / 256, 256, 0, stream>>>(x, Wq, Wk, Wv, pk,
                                            xb, wqb, wkb, wvb, kb);
  // 2. past_v -> outV rows [0,2048) + VT bf16 transpose
  v_copy_transpose<<<dim3(TPAST / 32, CD / 128, BB), 256, 0, stream>>>(pv, outV, vtb);
  // 3. Q (bf16, scaled) + V_new + K_new (rows 2048+, disjoint from S16)
  proj_qkv<<<dim3(MROWS / 128, 24), 256, 0, stream>>>(
      xb, wqb, wvb, wkb, bq, bv, bk, qb, outV, outK);
  // 4. scores -> bf16 S16 (per-batch overlay of outK rows [0,2048))
  score_gemm<<<dim3(TQ / 128, TPAST / 128, BB), 256, 0, stream>>>(qb, kb, S16);
  // 5. softmax rows in place (bf16 -> bf16)
  softmax_kernel<<<BB * TQ, 256, 0, stream>>>(S16);
  // 6. out = P @ V via VT
  pv_gemm<<<dim3(TQ / 128, CD / 128, BB), 256, 0, stream>>>(S16, vtb, out);
  // 7. past_k -> outK rows [0,2048) (wide grid; S16 fully consumed)
  copy_past_kernel<<<BB * TPAST * CD / 4 / 256, 256, 0, stream>>>(pk, outK);
}

// Round 6
// 238.187 us; speedup vs baseline: 1.1661x; 1.0094x over previous
//
#include <hip/hip_runtime.h>

// ---------------------------------------------------------------------------
// SelfAttention with KV cache, MI355X (gfx950).
// B=4, T=2048, C=1024, T_PAST=2048, T_TOT=4096.
// Mask tril(ones(T, T_total)) -> row t attends j<=t only => only past_k/v.
// Launches (6):
//   1. prep: [cvt] x,Wq,Wk,Wv->bf16, past_k->kb  +  [vct] past_v->outV rows
//      [0,2048) AND VT bf16 [b][c][s]            (one merged launch)
//   2. proj_qkv: Q->qb (bf16,scaled); V_new->outV[2048+); K_new->outK[2048+)
//   3. score_gemm: S = Q.kb^T -> bf16 S16 (overlay of outK rows [0,2048)/batch)
//   4. softmax: bf16 row -> bf16 P row in place (zeros beyond col t)
//   5. pv_gemm: out = P @ VT
//   6. copy_past: pk -> outK rows [0,2048)  (after pv consumed S16)
// All GEMMs: 128x128 tile, BK=32, 4 waves, global_load_lds w=16 into LINEAR
// LDS, now 2-PHASE DOUBLE-BUFFERED (T3 minimum recipe): issue STAGE(t+1)
// before computing tile t; single implicit vmcnt(0)+barrier per K-step hides
// HBM latency under ds_read+MFMA of the current tile.
// ---------------------------------------------------------------------------

typedef __bf16 bf16x8 __attribute__((ext_vector_type(8)));
typedef float f32x4 __attribute__((ext_vector_type(4)));

#define BB   4
#define TQ   2048
#define CD   1024
#define TPAST 2048
#define TTOT 4096
#define MROWS (BB * TQ)        // 8192
#define SSTRIDE ((size_t)TTOT * CD * 2)   // u16 units per batch window (16MB)

__device__ __forceinline__ unsigned short f32_to_bf16u(float f) {
  unsigned int u = __float_as_uint(f);
  u += 0x7FFFu + ((u >> 16) & 1u);       // RNE
  return (unsigned short)(u >> 16);
}
__device__ __forceinline__ float bf16u_to_f32(unsigned short h) {
  unsigned int u = ((unsigned int)h) << 16;
  return __uint_as_float(u);
}
__device__ __forceinline__ unsigned int pack_bf16(float a, float b) {
  return (unsigned int)f32_to_bf16u(a) | ((unsigned int)f32_to_bf16u(b) << 16);
}

// async global->LDS, 16B per lane; LDS dest = wave-uniform base + lane*16
__device__ __forceinline__ void gload_lds16(const unsigned short* g,
                                            unsigned short* l) {
  __builtin_amdgcn_global_load_lds(
      (const __attribute__((address_space(1))) void*)g,
      (__attribute__((address_space(3))) void*)l, 16, 0, 0);
}

// ---- merged prep: v_copy_transpose blocks [0,2048) + cvt blocks ------------
#define TP_PAD 134
#define VCT_BLOCKS 2048           // (2048/32) * (1024/128) * 4
#define R0_END 2097152            // x     : 8192*1024/4 f4
#define R1_END 2359296            // Wq    : +262144
#define R2_END 2621440            // Wk
#define R3_END 2883584            // Wv
#define R4_END 4980736            // past_k: +2097152
__global__ __launch_bounds__(256) void prep(
    const float* __restrict__ x, const float* __restrict__ wq,
    const float* __restrict__ wk, const float* __restrict__ wv,
    const float* __restrict__ pk, const float* __restrict__ pV,
    unsigned short* __restrict__ xb, unsigned short* __restrict__ wqb,
    unsigned short* __restrict__ wkb, unsigned short* __restrict__ wvb,
    unsigned short* __restrict__ kb,
    float* __restrict__ outV, unsigned short* __restrict__ VT) {
  const int tid = threadIdx.x;
  if (blockIdx.x < VCT_BLOCKS) {
    // ---- past_v -> outV copy + bf16 transpose VT[b][c][s] ----
    __shared__ unsigned short T[32 * TP_PAD];
    const int bid = blockIdx.x;
    const int s0 = (bid & 63) * 32, c0 = ((bid >> 6) & 7) * 128, b = bid >> 9;
    const int s = tid >> 3, i8 = tid & 7;
    const float* src = &pV[(size_t)(b * TPAST + s0 + s) * CD + c0];
    float* dst = &outV[(size_t)b * (TTOT * CD) + (size_t)(s0 + s) * CD + c0];
#pragma unroll
    for (int k = 0; k < 4; ++k) {
      int c = k * 32 + i8 * 4;
      float4 f = *(const float4*)&src[c];
      *(float4*)&dst[c] = f;
      *(unsigned int*)&T[s * TP_PAD + c]     = pack_bf16(f.x, f.y);
      *(unsigned int*)&T[s * TP_PAD + c + 2] = pack_bf16(f.z, f.w);
    }
    __syncthreads();
    const int c = tid >> 2, sq = tid & 3;
#pragma unroll
    for (int ii = 0; ii < 2; ++ii) {
      int cc = c + ii * 64;
      unsigned short tmp[8];
#pragma unroll
      for (int j = 0; j < 8; ++j) tmp[j] = T[(sq * 8 + j) * TP_PAD + cc];
      *(uint4*)&VT[(size_t)(b * CD + c0 + cc) * TPAST + s0 + sq * 8] = *(uint4*)tmp;
    }
    return;
  }
  // ---- bulk f32->bf16 conversions ----
  int i = (blockIdx.x - VCT_BLOCKS) * 256 + tid;
  const float* src; unsigned short* dst; int off;
  if (i < R0_END)      { src = x;  dst = xb;  off = i; }
  else if (i < R1_END) { src = wq; dst = wqb; off = i - R0_END; }
  else if (i < R2_END) { src = wk; dst = wkb; off = i - R1_END; }
  else if (i < R3_END) { src = wv; dst = wvb; off = i - R2_END; }
  else                 { src = pk; dst = kb;  off = i - R3_END; }
  float4 f = ((const float4*)src)[off];
  uint2 o;
  o.x = pack_bf16(f.x, f.y);
  o.y = pack_bf16(f.z, f.w);
  ((uint2*)dst)[off] = o;
}

// ---- copy past (4,2048,1024) into cache region (4,4096,1024) rows [0,2048) -
__global__ __launch_bounds__(256) void copy_past_kernel(
    const float* __restrict__ src, float* __restrict__ dst) {
  int i = blockIdx.x * 256 + threadIdx.x;      // float4 units
  int b = i >> 19;                             // 524288 units per batch
  int rem = i & 524287;
  ((float4*)dst)[(size_t)b * 1048576 + rem] = ((const float4*)src)[i];
}

// ---- merged Q+V+K projection, 2-phase double-buffered ----------------------
// y in [0,8): Q (bf16, scaled 1/32) -> qb
// y in [8,16): V_new (f32) -> outV rows [2048,4096)
// y in [16,24): K_new (f32) -> outK rows [2048,4096)
__global__ __launch_bounds__(256) void proj_qkv(
    const unsigned short* __restrict__ A,    // x bf16 [8192][1024]
    const unsigned short* __restrict__ Wq_,
    const unsigned short* __restrict__ Wv_,
    const unsigned short* __restrict__ Wk_,
    const float* __restrict__ bq_, const float* __restrict__ bv_,
    const float* __restrict__ bk_,
    unsigned short* __restrict__ outQ,       // bf16 [8192][1024]
    float* __restrict__ outV,                // f32 cache base (4,4096,1024)
    float* __restrict__ outK) {              // f32 cache base (4,4096,1024)
  __shared__ unsigned short sA[2][128 * 32];
  __shared__ unsigned short sB[2][128 * 32];
  const int tm = blockIdx.x * 128;
  const int which = blockIdx.y >> 3;         // 0=Q, 1=V, 2=K
  const int tn = (blockIdx.y & 7) * 128;
  const unsigned short* W = (which == 0) ? Wq_ : (which == 1) ? Wv_ : Wk_;
  const float* bias = (which == 0) ? bq_ : (which == 1) ? bv_ : bk_;
  const int tid = threadIdx.x, lane = tid & 63, wv = tid >> 6;
  const int wr = wv >> 1, wc = wv & 1;
  const int gr = lane >> 2, gc = (lane & 3) * 8;
  const unsigned short* aSrc = &A[(size_t)(tm + wv * 32 + gr) * CD + gc];
  const unsigned short* bSrc = &W[(size_t)(tn + wv * 32 + gr) * CD + gc];
  const int ldsOff = wv * 32 * 32;
  f32x4 acc[4][4] = {};
  const int NT = CD / 32;
  // prologue: stage tile 0
  gload_lds16(aSrc, &sA[0][ldsOff]);
  gload_lds16(aSrc + (size_t)16 * CD, &sA[0][ldsOff + 16 * 32]);
  gload_lds16(bSrc, &sB[0][ldsOff]);
  gload_lds16(bSrc + (size_t)16 * CD, &sB[0][ldsOff + 16 * 32]);
  __syncthreads();
  for (int t = 0; t < NT; ++t) {
    const int cur = t & 1;
    if (t + 1 < NT) {                        // stage next tile (async)
      const int k0 = (t + 1) * 32, nb = cur ^ 1;
      gload_lds16(aSrc + k0, &sA[nb][ldsOff]);
      gload_lds16(aSrc + k0 + (size_t)16 * CD, &sA[nb][ldsOff + 16 * 32]);
      gload_lds16(bSrc + k0, &sB[nb][ldsOff]);
      gload_lds16(bSrc + k0 + (size_t)16 * CD, &sB[nb][ldsOff + 16 * 32]);
    }
    bf16x8 af[4], bg[4];
    const int koff = (lane >> 4) * 8;
#pragma unroll
    for (int i = 0; i < 4; ++i)
      af[i] = *(const bf16x8*)&sA[cur][(wr * 64 + i * 16 + (lane & 15)) * 32 + koff];
#pragma unroll
    for (int i = 0; i < 4; ++i)
      bg[i] = *(const bf16x8*)&sB[cur][(wc * 64 + i * 16 + (lane & 15)) * 32 + koff];
#pragma unroll
    for (int mi = 0; mi < 4; ++mi)
#pragma unroll
      for (int ni = 0; ni < 4; ++ni)
        acc[mi][ni] = __builtin_amdgcn_mfma_f32_16x16x32_bf16(
            af[mi], bg[ni], acc[mi][ni], 0, 0, 0);
    __syncthreads();                         // drains vmcnt(0): next tile ready
  }
  const int rsub = (lane >> 4) * 4, csub = lane & 15;
#pragma unroll
  for (int mi = 0; mi < 4; ++mi)
#pragma unroll
    for (int ni = 0; ni < 4; ++ni) {
      int gcn = tn + wc * 64 + ni * 16 + csub;
      float bvv = bias[gcn];
#pragma unroll
      for (int r = 0; r < 4; ++r) {
        int grw = tm + wr * 64 + mi * 16 + rsub + r;
        float v = acc[mi][ni][r] + bvv;
        if (which == 0) {
          outQ[(size_t)grw * CD + gcn] = f32_to_bf16u(v * 0.03125f);  // 1/sqrt(1024)
        } else {
          int b = grw >> 11, t = grw & (TQ - 1);
          float* o = (which == 1) ? outV : outK;
          o[(size_t)b * (TTOT * CD) + (size_t)(TPAST + t) * CD + gcn] = v;
        }
      }
    }
}

// ---- scores: S16[b][t][s] = bf16( Q_scaled . kb^T ), 2-phase ---------------
__global__ __launch_bounds__(256) void score_gemm(
    const unsigned short* __restrict__ Q,   // bf16 [8192][1024], pre-scaled
    const unsigned short* __restrict__ KB,  // bf16 [4][2048][1024]
    unsigned short* __restrict__ S16) {     // bf16, per-batch window SSTRIDE
  const int t0 = blockIdx.x * 128, s0 = blockIdx.y * 128, b = blockIdx.z;
  if (s0 > t0 + 127) return;
  __shared__ unsigned short sA[2][128 * 32];
  __shared__ unsigned short sB[2][128 * 32];
  const int tid = threadIdx.x, lane = tid & 63, wv = tid >> 6;
  const int wr = wv >> 1, wc = wv & 1;
  const int gr = lane >> 2, gc = (lane & 3) * 8;
  const unsigned short* aSrc = &Q[(size_t)(b * TQ + t0 + wv * 32 + gr) * CD + gc];
  const unsigned short* bSrc = &KB[(size_t)(b * TPAST + s0 + wv * 32 + gr) * CD + gc];
  const int ldsOff = wv * 32 * 32;
  f32x4 acc[4][4] = {};
  const int NT = CD / 32;
  gload_lds16(aSrc, &sA[0][ldsOff]);
  gload_lds16(aSrc + (size_t)16 * CD, &sA[0][ldsOff + 16 * 32]);
  gload_lds16(bSrc, &sB[0][ldsOff]);
  gload_lds16(bSrc + (size_t)16 * CD, &sB[0][ldsOff + 16 * 32]);
  __syncthreads();
  for (int t = 0; t < NT; ++t) {
    const int cur = t & 1;
    if (t + 1 < NT) {
      const int k0 = (t + 1) * 32, nb = cur ^ 1;
      gload_lds16(aSrc + k0, &sA[nb][ldsOff]);
      gload_lds16(aSrc + k0 + (size_t)16 * CD, &sA[nb][ldsOff + 16 * 32]);
      gload_lds16(bSrc + k0, &sB[nb][ldsOff]);
      gload_lds16(bSrc + k0 + (size_t)16 * CD, &sB[nb][ldsOff + 16 * 32]);
    }
    bf16x8 af[4], bg[4];
    const int koff = (lane >> 4) * 8;
#pragma unroll
    for (int i = 0; i < 4; ++i)
      af[i] = *(const bf16x8*)&sA[cur][(wr * 64 + i * 16 + (lane & 15)) * 32 + koff];
#pragma unroll
    for (int i = 0; i < 4; ++i)
      bg[i] = *(const bf16x8*)&sB[cur][(wc * 64 + i * 16 + (lane & 15)) * 32 + koff];
#pragma unroll
    for (int mi = 0; mi < 4; ++mi)
#pragma unroll
      for (int ni = 0; ni < 4; ++ni)
        acc[mi][ni] = __builtin_amdgcn_mfma_f32_16x16x32_bf16(
            af[mi], bg[ni], acc[mi][ni], 0, 0, 0);
    __syncthreads();
  }
  const int rsub = (lane >> 4) * 4, csub = lane & 15;
#pragma unroll
  for (int mi = 0; mi < 4; ++mi)
#pragma unroll
    for (int ni = 0; ni < 4; ++ni) {
      int gs = s0 + wc * 64 + ni * 16 + csub;
#pragma unroll
      for (int r = 0; r < 4; ++r) {
        int gt = t0 + wr * 64 + mi * 16 + rsub + r;
        S16[(size_t)b * SSTRIDE + (size_t)gt * TPAST + gs] =
            f32_to_bf16u(acc[mi][ni][r]);
      }
    }
}

// ---- row softmax on bf16 S, in place -> bf16 P (zeros beyond col t) --------
__global__ __launch_bounds__(256) void softmax_kernel(unsigned short* __restrict__ S16) {
  const int row = blockIdx.x;               // 0..8191
  const int b = row >> 11, t = row & (TQ - 1);
  unsigned short* p = S16 + (size_t)b * SSTRIDE + (size_t)t * TPAST;
  const int tid = threadIdx.x, lane = tid & 63, wv = tid >> 6;
  __shared__ float red[8];
  const int base = tid * 8;
  uint4 raw = *(const uint4*)&p[base];
  const unsigned short* rw = (const unsigned short*)&raw;
  float v[8];
  float m = -3.0e38f;
#pragma unroll
  for (int i = 0; i < 8; ++i) {
    v[i] = (base + i <= t) ? bf16u_to_f32(rw[i]) : -3.0e38f;
    m = fmaxf(m, v[i]);
  }
#pragma unroll
  for (int off = 32; off >= 1; off >>= 1) m = fmaxf(m, __shfl_down(m, off));
  if (lane == 0) red[wv] = m;
  __syncthreads();
  if (tid == 0) red[4] = fmaxf(fmaxf(red[0], red[1]), fmaxf(red[2], red[3]));
  __syncthreads();
  const float rm = red[4];
  float e[8], s = 0.f;
#pragma unroll
  for (int i = 0; i < 8; ++i) {
    e[i] = (base + i <= t) ? __expf(v[i] - rm) : 0.f;
    s += e[i];
  }
#pragma unroll
  for (int off = 32; off >= 1; off >>= 1) s += __shfl_down(s, off);
  __syncthreads();
  if (lane == 0) red[wv] = s;
  __syncthreads();
  if (tid == 0) red[5] = red[0] + red[1] + red[2] + red[3];
  __syncthreads();
  const float inv = 1.f / red[5];
  unsigned short ob[8];
#pragma unroll
  for (int i = 0; i < 8; ++i) ob[i] = f32_to_bf16u(e[i] * inv);
  *(uint4*)&p[base] = *(uint4*)ob;
}

// ---- out = P(bf16) @ VT(bf16), 2-phase ; M=2048, N=1024(c), K=s ------------
__global__ __launch_bounds__(256) void pv_gemm(
    const unsigned short* __restrict__ Pb,  // bf16, per-batch window SSTRIDE
    const unsigned short* __restrict__ VT,  // bf16 [4][1024][2048]
    float* __restrict__ O) {                // f32 [4][2048][1024]
  const int t0 = blockIdx.x * 128, c0 = blockIdx.y * 128, b = blockIdx.z;
  __shared__ unsigned short sA[2][128 * 32];
  __shared__ unsigned short sB[2][128 * 32];
  const int tid = threadIdx.x, lane = tid & 63, wv = tid >> 6;
  const int wr = wv >> 1, wc = wv & 1;
  const int gr = lane >> 2, gc = (lane & 3) * 8;
  const unsigned short* aSrc =
      &Pb[(size_t)b * SSTRIDE + (size_t)(t0 + wv * 32 + gr) * TPAST + gc];
  const unsigned short* bSrc =
      &VT[(size_t)(b * CD + c0 + wv * 32 + gr) * TPAST + gc];
  const int ldsOff = wv * 32 * 32;
  f32x4 acc[4][4] = {};
  const int s_end = (t0 + 128 < TPAST) ? (t0 + 128) : TPAST;  // P==0 past t
  const int NT = s_end / 32;
  gload_lds16(aSrc, &sA[0][ldsOff]);
  gload_lds16(aSrc + (size_t)16 * TPAST, &sA[0][ldsOff + 16 * 32]);
  gload_lds16(bSrc, &sB[0][ldsOff]);
  gload_lds16(bSrc + (size_t)16 * TPAST, &sB[0][ldsOff + 16 * 32]);
  __syncthreads();
  for (int t = 0; t < NT; ++t) {
    const int cur = t & 1;
    if (t + 1 < NT) {
      const int s0 = (t + 1) * 32, nb = cur ^ 1;
      gload_lds16(aSrc + s0, &sA[nb][ldsOff]);
      gload_lds16(aSrc + s0 + (size_t)16 * TPAST, &sA[nb][ldsOff + 16 * 32]);
      gload_lds16(bSrc + s0, &sB[nb][ldsOff]);
      gload_lds16(bSrc + s0 + (size_t)16 * TPAST, &sB[nb][ldsOff + 16 * 32]);
    }
    bf16x8 af[4], bg[4];
    const int koff = (lane >> 4) * 8;
#pragma unroll
    for (int i = 0; i < 4; ++i)
      af[i] = *(const bf16x8*)&sA[cur][(wr * 64 + i * 16 + (lane & 15)) * 32 + koff];
#pragma unroll
    for (int i = 0; i < 4; ++i)
      bg[i] = *(const bf16x8*)&sB[cur][(wc * 64 + i * 16 + (lane & 15)) * 32 + koff];
#pragma unroll
    for (int mi = 0; mi < 4; ++mi)
#pragma unroll
      for (int ni = 0; ni < 4; ++ni)
        acc[mi][ni] = __builtin_amdgcn_mfma_f32_16x16x32_bf16(
            af[mi], bg[ni], acc[mi][ni], 0, 0, 0);
    __syncthreads();
  }
  const int rsub = (lane >> 4) * 4, csub = lane & 15;
#pragma unroll
  for (int mi = 0; mi < 4; ++mi)
#pragma unroll
    for (int ni = 0; ni < 4; ++ni) {
      int gcn = c0 + wc * 64 + ni * 16 + csub;
#pragma unroll
      for (int r = 0; r < 4; ++r) {
        int gt = t0 + wr * 64 + mi * 16 + rsub + r;
        O[(size_t)(b * TQ + gt) * CD + gcn] = acc[mi][ni][r];
      }
    }
}

extern "C" void kernel_launch(void* const* d_in, const int* in_sizes, int n_in,
                              void* d_out, int out_size, void* d_ws, size_t ws_size,
                              hipStream_t stream) {
  const float* x  = (const float*)d_in[0];
  const float* pk = (const float*)d_in[1];
  const float* pv = (const float*)d_in[2];
  const float* Wq = (const float*)d_in[3];
  const float* bq = (const float*)d_in[4];
  const float* Wk = (const float*)d_in[5];
  const float* bk = (const float*)d_in[6];
  const float* Wv = (const float*)d_in[7];
  const float* bv = (const float*)d_in[8];

  float* out  = (float*)d_out;                       // (4,2048,1024)
  float* outK = out + (size_t)BB * TQ * CD;          // (4,4096,1024)
  float* outV = outK + (size_t)BB * TTOT * CD;       // (4,4096,1024)
  // S16 bf16 [2048][2048] per batch, overlaying batch b's outK rows [0,2048)
  unsigned short* S16 = (unsigned short*)outK;

  unsigned short* xb  = (unsigned short*)d_ws;       // 8192*1024 bf16
  unsigned short* wqb = xb + (size_t)MROWS * CD;
  unsigned short* wkb = wqb + (size_t)CD * CD;
  unsigned short* wvb = wkb + (size_t)CD * CD;
  unsigned short* qb  = wvb + (size_t)CD * CD;       // 8192*1024 bf16
  unsigned short* vtb = qb + (size_t)MROWS * CD;     // 4*1024*2048 bf16 (V^T)
  unsigned short* kb  = vtb + (size_t)BB * CD * TPAST; // 4*2048*1024 bf16

  // 1. merged conversions + past_v copy/transpose
  prep<<<VCT_BLOCKS + R4_END / 256, 256, 0, stream>>>(
      x, Wq, Wk, Wv, pk, pv, xb, wqb, wkb, wvb, kb, outV, vtb);
  // 2. Q (bf16, scaled) + V_new + K_new (rows 2048+, disjoint from S16)
  proj_qkv<<<dim3(MROWS / 128, 24), 256, 0, stream>>>(
      xb, wqb, wvb, wkb, bq, bv, bk, qb, outV, outK);
  // 3. scores -> bf16 S16 (per-batch overlay of outK rows [0,2048))
  score_gemm<<<dim3(TQ / 128, TPAST / 128, BB), 256, 0, stream>>>(qb, kb, S16);
  // 4. softmax rows in place (bf16 -> bf16)
  softmax_kernel<<<BB * TQ, 256, 0, stream>>>(S16);
  // 5. out = P @ V via VT
  pv_gemm<<<dim3(TQ / 128, CD / 128, BB), 256, 0, stream>>>(S16, vtb, out);
  // 6. past_k -> outK rows [0,2048) (wide grid; S16 fully consumed)
  copy_past_kernel<<<BB * TPAST * CD / 4 / 256, 256, 0, stream>>>(pk, outK);
}

// Round 7
// 215.756 us; speedup vs baseline: 1.2874x; 1.1040x over previous
//
#include <hip/hip_runtime.h>

// ---------------------------------------------------------------------------
// SelfAttention with KV cache, MI355X (gfx950).
// B=4, T=2048, C=1024, T_PAST=2048, T_TOT=4096.
// Mask tril(ones(T, T_total)) -> row t attends j<=t only => only past_k/v.
// Launches (6):
//   1. prep: cvt x,Wq,Wk,Wv,past_k -> bf16 + past_v->outV copy + VT transpose
//   2. proj_qkv: Q->qb (bf16,scaled); V_new->outV[2048+); K_new->outK[2048+)
//   3. score_gemm: S = Q.kb^T -> bf16 S16 (overlay outK rows [0,2048)/batch)
//   4. softmax: bf16 row -> bf16 P row in place (zeros beyond col t)
//   5. pv_gemm: out = P @ VT
//   6. copy_past: pk -> outK rows [0,2048)  (after pv consumed S16)
//
// GEMM core v2 (this round): 128x128 tile, BK=32, 4 waves, 3-slot LDS ring
// (48KB), counted vmcnt(8) that NEVER drains to 0 in the main loop (loads
// stay 2 K-steps in flight across barriers), raw s_barrier pairs, XOR
// read-swizzle (phys 16B-group = logical ^ (row&3)) with pre-swizzled global
// source (gload_lds writes linear), lgkmcnt(0)+sched_barrier before the
// read-release barrier, setprio(1) around the MFMA cluster.
// ---------------------------------------------------------------------------

typedef __bf16 bf16x8 __attribute__((ext_vector_type(8)));
typedef float f32x4 __attribute__((ext_vector_type(4)));

#define BB   4
#define TQ   2048
#define CD   1024
#define TPAST 2048
#define TTOT 4096
#define MROWS (BB * TQ)        // 8192
#define SSTRIDE ((size_t)TTOT * CD * 2)   // u16 units per batch window (16MB)
#define SLOTU 8192             // u16 per ring slot (A 8KB + B 8KB = 16KB)

__device__ __forceinline__ unsigned short f32_to_bf16u(float f) {
  unsigned int u = __float_as_uint(f);
  u += 0x7FFFu + ((u >> 16) & 1u);       // RNE
  return (unsigned short)(u >> 16);
}
__device__ __forceinline__ float bf16u_to_f32(unsigned short h) {
  unsigned int u = ((unsigned int)h) << 16;
  return __uint_as_float(u);
}
__device__ __forceinline__ unsigned int pack_bf16(float a, float b) {
  return (unsigned int)f32_to_bf16u(a) | ((unsigned int)f32_to_bf16u(b) << 16);
}

// async global->LDS, 16B per lane; LDS dest = wave-uniform base + lane*16
__device__ __forceinline__ void gload_lds16(const unsigned short* g,
                                            unsigned short* l) {
  __builtin_amdgcn_global_load_lds(
      (const __attribute__((address_space(1))) void*)g,
      (__attribute__((address_space(3))) void*)l, 16, 0, 0);
}

// ---------------------------------------------------------------------------
// GEMM core v2. Per thread: pa0/pa1/pb0/pb1 are pre-swizzled global srcs
// (row + 16B-group permutation baked in), advanced +32 u16 per staged K-step.
// lds = 3*SLOTU u16. acc[4][4] accumulated. All branches wave-uniform.
// ---------------------------------------------------------------------------
struct StagePtrs {
  const unsigned short *a0, *a1, *b0, *b1;
};

__device__ __forceinline__ void stage_step(StagePtrs& p, unsigned short* lds,
                                           int stOff, int wv) {
  unsigned short* base = lds + stOff + wv * 512;
  gload_lds16(p.a0, base);
  gload_lds16(p.a1, base + 2048);
  gload_lds16(p.b0, base + 4096);
  gload_lds16(p.b1, base + 6144);
  p.a0 += 32; p.a1 += 32; p.b0 += 32; p.b1 += 32;
}

__device__ __forceinline__ void gemm_core_v2(
    StagePtrs p, unsigned short* lds, int NT,
    int wr, int wc, int lane, int wv, f32x4 acc[4][4]) {
  // read addressing: logical k-group = lane>>4; physical = logical ^ (row&3),
  // row&3 == lane&3 for all fragment rows (row = base16 + (lane&15)).
  const int gph8 = (((lane >> 4) ^ (lane & 3))) * 8;
  const int aRd = (wr * 64 + (lane & 15)) * 32 + gph8;
  const int bRd = 4096 + (wc * 64 + (lane & 15)) * 32 + gph8;

  // prologue: stage K-steps 0 and 1 into slots 0 and 1
  stage_step(p, lds, 0, wv);
  stage_step(p, lds, SLOTU, wv);
  int stOff = 2 * SLOTU;     // slot for t+2
  int rdOff = 0;             // slot for t

  for (int t = 0; t < NT; ++t) {
    if (t + 2 < NT) {
      stage_step(p, lds, stOff, wv);
      stOff = (stOff == 2 * SLOTU) ? 0 : stOff + SLOTU;
    }
    const int rem = NT - 1 - t;
    if (rem >= 2)      asm volatile("s_waitcnt vmcnt(8)" ::: "memory");
    else if (rem == 1) asm volatile("s_waitcnt vmcnt(4)" ::: "memory");
    else               asm volatile("s_waitcnt vmcnt(0)" ::: "memory");
    asm volatile("s_barrier" ::: "memory");       // B1: slot t resident
    bf16x8 af[4], bg[4];
#pragma unroll
    for (int i = 0; i < 4; ++i)
      af[i] = *(const bf16x8*)&lds[rdOff + aRd + i * 512];
#pragma unroll
    for (int i = 0; i < 4; ++i)
      bg[i] = *(const bf16x8*)&lds[rdOff + bRd + i * 512];
    asm volatile("s_waitcnt lgkmcnt(0)" ::: "memory");
    __builtin_amdgcn_sched_barrier(0);
    asm volatile("s_barrier" ::: "memory");       // B2: all reads done
    __builtin_amdgcn_s_setprio(1);
#pragma unroll
    for (int mi = 0; mi < 4; ++mi)
#pragma unroll
      for (int ni = 0; ni < 4; ++ni)
        acc[mi][ni] = __builtin_amdgcn_mfma_f32_16x16x32_bf16(
            af[mi], bg[ni], acc[mi][ni], 0, 0, 0);
    __builtin_amdgcn_s_setprio(0);
    rdOff = (rdOff == 2 * SLOTU) ? 0 : rdOff + SLOTU;
  }
}

// per-thread pre-swizzled source pointer for one operand tile.
// rowInTile = part*64 + wv*16 + (lane>>2); 16B-group g' = (lane&3)^((lane>>2)&3)
__device__ __forceinline__ const unsigned short* swz_src(
    const unsigned short* base, size_t rowStart, size_t ld,
    int part, int wv, int lane) {
  int row = part * 64 + wv * 16 + (lane >> 2);
  int gp = (lane & 3) ^ ((lane >> 2) & 3);
  return base + (rowStart + row) * ld + gp * 8;
}

// ---- merged prep: v_copy_transpose blocks + cvt blocks ---------------------
#define TP_PAD 134
#define VCT_BLOCKS 2048           // (2048/32) * (1024/128) * 4
#define R0_END 2097152            // x     : 8192*1024/4 f4
#define R1_END 2359296            // Wq    : +262144
#define R2_END 2621440            // Wk
#define R3_END 2883584            // Wv
#define R4_END 4980736            // past_k: +2097152
__global__ __launch_bounds__(256) void prep(
    const float* __restrict__ x, const float* __restrict__ wq,
    const float* __restrict__ wk, const float* __restrict__ wv,
    const float* __restrict__ pk, const float* __restrict__ pV,
    unsigned short* __restrict__ xb, unsigned short* __restrict__ wqb,
    unsigned short* __restrict__ wkb, unsigned short* __restrict__ wvb,
    unsigned short* __restrict__ kb,
    float* __restrict__ outV, unsigned short* __restrict__ VT) {
  const int tid = threadIdx.x;
  if (blockIdx.x < VCT_BLOCKS) {
    __shared__ unsigned short T[32 * TP_PAD];
    const int bid = blockIdx.x;
    const int s0 = (bid & 63) * 32, c0 = ((bid >> 6) & 7) * 128, b = bid >> 9;
    const int s = tid >> 3, i8 = tid & 7;
    const float* src = &pV[(size_t)(b * TPAST + s0 + s) * CD + c0];
    float* dst = &outV[(size_t)b * (TTOT * CD) + (size_t)(s0 + s) * CD + c0];
#pragma unroll
    for (int k = 0; k < 4; ++k) {
      int c = k * 32 + i8 * 4;
      float4 f = *(const float4*)&src[c];
      *(float4*)&dst[c] = f;
      *(unsigned int*)&T[s * TP_PAD + c]     = pack_bf16(f.x, f.y);
      *(unsigned int*)&T[s * TP_PAD + c + 2] = pack_bf16(f.z, f.w);
    }
    __syncthreads();
    const int c = tid >> 2, sq = tid & 3;
#pragma unroll
    for (int ii = 0; ii < 2; ++ii) {
      int cc = c + ii * 64;
      unsigned short tmp[8];
#pragma unroll
      for (int j = 0; j < 8; ++j) tmp[j] = T[(sq * 8 + j) * TP_PAD + cc];
      *(uint4*)&VT[(size_t)(b * CD + c0 + cc) * TPAST + s0 + sq * 8] = *(uint4*)tmp;
    }
    return;
  }
  int i = (blockIdx.x - VCT_BLOCKS) * 256 + tid;
  const float* src; unsigned short* dst; int off;
  if (i < R0_END)      { src = x;  dst = xb;  off = i; }
  else if (i < R1_END) { src = wq; dst = wqb; off = i - R0_END; }
  else if (i < R2_END) { src = wk; dst = wkb; off = i - R1_END; }
  else if (i < R3_END) { src = wv; dst = wvb; off = i - R2_END; }
  else                 { src = pk; dst = kb;  off = i - R3_END; }
  float4 f = ((const float4*)src)[off];
  uint2 o;
  o.x = pack_bf16(f.x, f.y);
  o.y = pack_bf16(f.z, f.w);
  ((uint2*)dst)[off] = o;
}

// ---- copy past (4,2048,1024) into cache region rows [0,2048) ---------------
__global__ __launch_bounds__(256) void copy_past_kernel(
    const float* __restrict__ src, float* __restrict__ dst) {
  int i = blockIdx.x * 256 + threadIdx.x;      // float4 units
  int b = i >> 19;
  int rem = i & 524287;
  ((float4*)dst)[(size_t)b * 1048576 + rem] = ((const float4*)src)[i];
}

// ---- merged Q+V+K projection (v2 core) --------------------------------------
__global__ __launch_bounds__(256, 3) void proj_qkv(
    const unsigned short* __restrict__ A,    // x bf16 [8192][1024]
    const unsigned short* __restrict__ Wq_,
    const unsigned short* __restrict__ Wv_,
    const unsigned short* __restrict__ Wk_,
    const float* __restrict__ bq_, const float* __restrict__ bv_,
    const float* __restrict__ bk_,
    unsigned short* __restrict__ outQ,
    float* __restrict__ outV, float* __restrict__ outK) {
  __shared__ unsigned short lds[3 * SLOTU];
  const int tm = blockIdx.x * 128;
  const int which = blockIdx.y >> 3;         // 0=Q, 1=V, 2=K
  const int tn = (blockIdx.y & 7) * 128;
  const unsigned short* W = (which == 0) ? Wq_ : (which == 1) ? Wv_ : Wk_;
  const float* bias = (which == 0) ? bq_ : (which == 1) ? bv_ : bk_;
  const int tid = threadIdx.x, lane = tid & 63, wv = tid >> 6;
  const int wr = wv >> 1, wc = wv & 1;
  StagePtrs p;
  p.a0 = swz_src(A, tm, CD, 0, wv, lane);
  p.a1 = swz_src(A, tm, CD, 1, wv, lane);
  p.b0 = swz_src(W, tn, CD, 0, wv, lane);
  p.b1 = swz_src(W, tn, CD, 1, wv, lane);
  f32x4 acc[4][4] = {};
  gemm_core_v2(p, lds, CD / 32, wr, wc, lane, wv, acc);
  const int rsub = (lane >> 4) * 4, csub = lane & 15;
#pragma unroll
  for (int mi = 0; mi < 4; ++mi)
#pragma unroll
    for (int ni = 0; ni < 4; ++ni) {
      int gcn = tn + wc * 64 + ni * 16 + csub;
      float bvv = bias[gcn];
#pragma unroll
      for (int r = 0; r < 4; ++r) {
        int grw = tm + wr * 64 + mi * 16 + rsub + r;
        float v = acc[mi][ni][r] + bvv;
        if (which == 0) {
          outQ[(size_t)grw * CD + gcn] = f32_to_bf16u(v * 0.03125f);  // 1/sqrt(1024)
        } else {
          int b = grw >> 11, t = grw & (TQ - 1);
          float* o = (which == 1) ? outV : outK;
          o[(size_t)b * (TTOT * CD) + (size_t)(TPAST + t) * CD + gcn] = v;
        }
      }
    }
}

// ---- scores: S16[b][t][s] = bf16( Q_scaled . kb^T ) (v2 core) ---------------
__global__ __launch_bounds__(256, 3) void score_gemm(
    const unsigned short* __restrict__ Q,
    const unsigned short* __restrict__ KB,
    unsigned short* __restrict__ S16) {
  const int t0 = blockIdx.x * 128, s0 = blockIdx.y * 128, b = blockIdx.z;
  if (s0 > t0 + 127) return;
  __shared__ unsigned short lds[3 * SLOTU];
  const int tid = threadIdx.x, lane = tid & 63, wv = tid >> 6;
  const int wr = wv >> 1, wc = wv & 1;
  StagePtrs p;
  p.a0 = swz_src(Q, (size_t)b * TQ + t0, CD, 0, wv, lane);
  p.a1 = swz_src(Q, (size_t)b * TQ + t0, CD, 1, wv, lane);
  p.b0 = swz_src(KB, (size_t)b * TPAST + s0, CD, 0, wv, lane);
  p.b1 = swz_src(KB, (size_t)b * TPAST + s0, CD, 1, wv, lane);
  f32x4 acc[4][4] = {};
  gemm_core_v2(p, lds, CD / 32, wr, wc, lane, wv, acc);
  const int rsub = (lane >> 4) * 4, csub = lane & 15;
#pragma unroll
  for (int mi = 0; mi < 4; ++mi)
#pragma unroll
    for (int ni = 0; ni < 4; ++ni) {
      int gs = s0 + wc * 64 + ni * 16 + csub;
#pragma unroll
      for (int r = 0; r < 4; ++r) {
        int gt = t0 + wr * 64 + mi * 16 + rsub + r;
        S16[(size_t)b * SSTRIDE + (size_t)gt * TPAST + gs] =
            f32_to_bf16u(acc[mi][ni][r]);
      }
    }
}

// ---- row softmax on bf16 S, in place -> bf16 P (zeros beyond col t) --------
__global__ __launch_bounds__(256) void softmax_kernel(unsigned short* __restrict__ S16) {
  const int row = blockIdx.x;               // 0..8191
  const int b = row >> 11, t = row & (TQ - 1);
  unsigned short* p = S16 + (size_t)b * SSTRIDE + (size_t)t * TPAST;
  const int tid = threadIdx.x, lane = tid & 63, wv = tid >> 6;
  __shared__ float red[8];
  const int base = tid * 8;
  uint4 raw = *(const uint4*)&p[base];
  const unsigned short* rw = (const unsigned short*)&raw;
  float v[8];
  float m = -3.0e38f;
#pragma unroll
  for (int i = 0; i < 8; ++i) {
    v[i] = (base + i <= t) ? bf16u_to_f32(rw[i]) : -3.0e38f;
    m = fmaxf(m, v[i]);
  }
#pragma unroll
  for (int off = 32; off >= 1; off >>= 1) m = fmaxf(m, __shfl_down(m, off));
  if (lane == 0) red[wv] = m;
  __syncthreads();
  if (tid == 0) red[4] = fmaxf(fmaxf(red[0], red[1]), fmaxf(red[2], red[3]));
  __syncthreads();
  const float rm = red[4];
  float e[8], s = 0.f;
#pragma unroll
  for (int i = 0; i < 8; ++i) {
    e[i] = (base + i <= t) ? __expf(v[i] - rm) : 0.f;
    s += e[i];
  }
#pragma unroll
  for (int off = 32; off >= 1; off >>= 1) s += __shfl_down(s, off);
  __syncthreads();
  if (lane == 0) red[wv] = s;
  __syncthreads();
  if (tid == 0) red[5] = red[0] + red[1] + red[2] + red[3];
  __syncthreads();
  const float inv = 1.f / red[5];
  unsigned short ob[8];
#pragma unroll
  for (int i = 0; i < 8; ++i) ob[i] = f32_to_bf16u(e[i] * inv);
  *(uint4*)&p[base] = *(uint4*)ob;
}

// ---- out = P(bf16) @ VT(bf16) (v2 core) -------------------------------------
__global__ __launch_bounds__(256, 3) void pv_gemm(
    const unsigned short* __restrict__ Pb,  // bf16, per-batch window SSTRIDE
    const unsigned short* __restrict__ VT,  // bf16 [4][1024][2048]
    float* __restrict__ O) {
  const int t0 = blockIdx.x * 128, c0 = blockIdx.y * 128, b = blockIdx.z;
  __shared__ unsigned short lds[3 * SLOTU];
  const int tid = threadIdx.x, lane = tid & 63, wv = tid >> 6;
  const int wr = wv >> 1, wc = wv & 1;
  StagePtrs p;
  p.a0 = swz_src(Pb + (size_t)b * SSTRIDE, t0, TPAST, 0, wv, lane);
  p.a1 = swz_src(Pb + (size_t)b * SSTRIDE, t0, TPAST, 1, wv, lane);
  p.b0 = swz_src(VT, (size_t)b * CD + c0, TPAST, 0, wv, lane);
  p.b1 = swz_src(VT, (size_t)b * CD + c0, TPAST, 1, wv, lane);
  f32x4 acc[4][4] = {};
  const int s_end = (t0 + 128 < TPAST) ? (t0 + 128) : TPAST;  // P==0 past t
  gemm_core_v2(p, lds, s_end / 32, wr, wc, lane, wv, acc);
  const int rsub = (lane >> 4) * 4, csub = lane & 15;
#pragma unroll
  for (int mi = 0; mi < 4; ++mi)
#pragma unroll
    for (int ni = 0; ni < 4; ++ni) {
      int gcn = c0 + wc * 64 + ni * 16 + csub;
#pragma unroll
      for (int r = 0; r < 4; ++r) {
        int gt = t0 + wr * 64 + mi * 16 + rsub + r;
        O[(size_t)(b * TQ + gt) * CD + gcn] = acc[mi][ni][r];
      }
    }
}

extern "C" void kernel_launch(void* const* d_in, const int* in_sizes, int n_in,
                              void* d_out, int out_size, void* d_ws, size_t ws_size,
                              hipStream_t stream) {
  const float* x  = (const float*)d_in[0];
  const float* pk = (const float*)d_in[1];
  const float* pv = (const float*)d_in[2];
  const float* Wq = (const float*)d_in[3];
  const float* bq = (const float*)d_in[4];
  const float* Wk = (const float*)d_in[5];
  const float* bk = (const float*)d_in[6];
  const float* Wv = (const float*)d_in[7];
  const float* bv = (const float*)d_in[8];

  float* out  = (float*)d_out;                       // (4,2048,1024)
  float* outK = out + (size_t)BB * TQ * CD;          // (4,4096,1024)
  float* outV = outK + (size_t)BB * TTOT * CD;       // (4,4096,1024)
  // S16 bf16 [2048][2048] per batch, overlaying batch b's outK rows [0,2048)
  unsigned short* S16 = (unsigned short*)outK;

  unsigned short* xb  = (unsigned short*)d_ws;       // 8192*1024 bf16
  unsigned short* wqb = xb + (size_t)MROWS * CD;
  unsigned short* wkb = wqb + (size_t)CD * CD;
  unsigned short* wvb = wkb + (size_t)CD * CD;
  unsigned short* qb  = wvb + (size_t)CD * CD;       // 8192*1024 bf16
  unsigned short* vtb = qb + (size_t)MROWS * CD;     // 4*1024*2048 bf16 (V^T)
  unsigned short* kb  = vtb + (size_t)BB * CD * TPAST; // 4*2048*1024 bf16

  // 1. merged conversions + past_v copy/transpose
  prep<<<VCT_BLOCKS + R4_END / 256, 256, 0, stream>>>(
      x, Wq, Wk, Wv, pk, pv, xb, wqb, wkb, wvb, kb, outV, vtb);
  // 2. Q (bf16, scaled) + V_new + K_new (rows 2048+, disjoint from S16)
  proj_qkv<<<dim3(MROWS / 128, 24), 256, 0, stream>>>(
      xb, wqb, wvb, wkb, bq, bv, bk, qb, outV, outK);
  // 3. scores -> bf16 S16 (per-batch overlay of outK rows [0,2048))
  score_gemm<<<dim3(TQ / 128, TPAST / 128, BB), 256, 0, stream>>>(qb, kb, S16);
  // 4. softmax rows in place (bf16 -> bf16)
  softmax_kernel<<<BB * TQ, 256, 0, stream>>>(S16);
  // 5. out = P @ V via VT
  pv_gemm<<<dim3(TQ / 128, CD / 128, BB), 256, 0, stream>>>(S16, vtb, out);
  // 6. past_k -> outK rows [0,2048) (wide grid; S16 fully consumed)
  copy_past_kernel<<<BB * TPAST * CD / 4 / 256, 256, 0, stream>>>(pk, outK);
}